// Round 10
// baseline (677.488 us; speedup 1.0000x reference)
//
#include <hip/hip_runtime.h>
#include <hip/hip_bf16.h>

using bf16 = __hip_bfloat16;
typedef __bf16 bf16x8 __attribute__((ext_vector_type(8)));
typedef float f32x4 __attribute__((ext_vector_type(4)));

#define DEV static __device__ __forceinline__

// ---------------------------------------------------------------------------
DEV void gld_lds16(const bf16* g, bf16* l) {
  __builtin_amdgcn_global_load_lds((__attribute__((address_space(1))) void*)g,
                                   (__attribute__((address_space(3))) void*)l,
                                   16, 0, 0);
}

// LDS chunk swizzle. Chosen so BOTH access patterns in play are >=8-spread:
//  - attn kf rows: base + (cc>>2)*8 + (cc&3)  -> bits r[1:0], r[3] vary
//  - attn vf / gemm rows: base16*k + cc       -> bits r[1:0], r[3] vary
// (R0 measured: old (r&7) swz -> SQ_LDS_BANK_CONFLICT == kf_reads*4 == 2^22
//  exactly; R2 measured: this swz -> 0 conflicts.)
DEV int swz(int r) { return (r & 3) | (((r >> 3) & 1) << 2); }

// Stage (NCHUNK/8) rows x 64 cols bf16 (row stride gs) into LDS, XOR-swizzled.
template<int NCHUNK>
DEV void stage_tile(const bf16* g, int gs, bf16* lds) {
  const int tid = threadIdx.x;
  const int w = tid >> 6, lane = tid & 63;
#pragma unroll
  for (int i = 0; i < NCHUNK / 256; ++i) {
    const int pb = i * 256 + w * 64;   // wave-uniform chunk base
    const int p  = pb + lane;
    const int r  = p >> 3;
    const int c  = (p & 7) ^ swz(r);
    gld_lds16(g + r * gs + c * 8, lds + pb * 8);
  }
}

DEV bf16x8 frag(const bf16* lds, int row, int cchunk) {
  const int p = row * 8 + (cchunk ^ swz(row));
  return *(const bf16x8*)(lds + p * 8);
}

// Packed f32x2 -> bf16x2 in ONE instruction (RNE). hip_bf16's
// __float2bfloat16 lowers to a multi-instr software-RNE sequence; at
// 2.68e8 conversions in attn that was ~7us of VALU (R4: 88.4->81us).
DEV unsigned pk2(float a, float b) {
  unsigned r;
  asm("v_cvt_pk_bf16_f32 %0, %1, %2" : "=v"(r) : "v"(a), "v"(b));
  return r;
}

union FragU { int i[4]; bf16x8 v; };

// ---------------------------------------------------------------------------
// prep: fp32->bf16 convert (blocks [0,2048)) + W transposes (blocks [2048,5120))
// Wq transpose folds scale = 0.125 * log2(e) so attention uses HW exp2.
// (R9 lesson: fusing the convert into gemm's staging reg-path serializes
// global->cvt->ds_write before the barrier -> gemm 66->127us. Keep prep.)
__global__ void prep(const float4* __restrict__ x, ushort4* __restrict__ xb,
                     const float4* __restrict__ ctx, ushort4* __restrict__ cb,
                     const float* __restrict__ wq, bf16* __restrict__ wqt,
                     const float* __restrict__ wkv, bf16* __restrict__ wkvt) {
  __shared__ float t[32][33];
  const int tid = threadIdx.x;
  if (blockIdx.x < 2048) {
    int i = blockIdx.x * 256 + tid;
    const int stride = 2048 * 256;
#pragma unroll
    for (int s = 0; s < 4; ++s, i += stride) {
      float4 a = x[i];
      float4 b = ctx[i];
      union { ushort4 u; unsigned v[2]; } oa, ob;
      oa.v[0] = pk2(a.x, a.y); oa.v[1] = pk2(a.z, a.w);
      ob.v[0] = pk2(b.x, b.y); ob.v[1] = pk2(b.z, b.w);
      xb[i] = oa.u;
      cb[i] = ob.u;
    }
    return;
  }
  const int tb = blockIdx.x - 2048;      // 3072 = 96 x 32
  int bx = tb % 96;
  const int by = tb / 96;
  const float* in; bf16* out; int N; float scale;
  if (bx < 32) { in = wq;  out = wqt;  N = 1024; scale = 0.18033688011112042f; }
  else         { in = wkv; out = wkvt; N = 2048; scale = 1.0f; bx -= 32; }
  const int k0 = by * 32, n0 = bx * 32;
  const int tx = tid & 31, ty = tid >> 5;  // 32 x 8
#pragma unroll
  for (int s = 0; s < 4; ++s)
    t[ty + 8 * s][tx] = in[(size_t)(k0 + ty + 8 * s) * N + n0 + tx];
  __syncthreads();
#pragma unroll
  for (int s = 0; s < 4; ++s)
    out[(size_t)(n0 + ty + 8 * s) * 1024 + k0 + tx] =
        __float2bfloat16(t[tx][ty + 8 * s] * scale);
}

// ---------------------------------------------------------------------------
// Merged q/kv GEMM. R10: SINGLE-BUFFERED 32KB LDS, 4 blocks/CU (attn's
// structure). R9's counters showed gemm at 2 blocks/CU is latency-bound
// (Occupancy 21%, both pipes <16%); attn's identical stage->barrier->
// compute->barrier loop at 4 blocks/CU hits MfmaUtil 44 via TLP (R1/m114).
// The dbuf bought nothing at 2 blocks/CU that 4-block TLP doesn't buy better.
// R7: XCD-aware M-stripe mapping (XCD c owns m-panels [c*8,c*8+8), n fastest).
// blocks [0,512) = q, [512,1536) = kv.
// q/k blocks: SWAPPED operands -> C^T. v blocks: normal.
// Epilogue reuses the 32KB buffer (both tile layouts are exactly 32KB).
__global__ __launch_bounds__(256, 4)
void gemm_all(const bf16* __restrict__ xb, const bf16* __restrict__ cb,
              const bf16* __restrict__ wqt, const bf16* __restrict__ wkvt,
              bf16* __restrict__ qb, bf16* __restrict__ kb, bf16* __restrict__ vtb) {
  __shared__ alignas(16) bf16 smem[128 * 64 * 2];   // 32 KB: A tile + B tile
  const int id = blockIdx.x;
  const bool isq = id < 512;
  const bf16* A; const bf16* Bt; int m0, n0;
  if (isq) {
    A = xb; Bt = wqt;
    const int c = id & 7, j = id >> 3;         // j in [0,64)
    n0 = (j & 7) * 128;
    m0 = (c * 8 + (j >> 3)) * 128;             // m-index in [0,64)
  } else {
    const int id2 = id - 512;
    A = cb; Bt = wkvt;
    const int c = id2 & 7, j = id2 >> 3;       // j in [0,128)
    n0 = (j & 15) * 128;
    m0 = (c * 8 + (j >> 4)) * 128;             // m-index in [0,64)
  }
  const bool swapped = isq || (n0 < 1024);   // q and k blocks
  const int tid = threadIdx.x, lane = tid & 63, w = tid >> 6;
  const int q4 = lane >> 4, cc = lane & 15;
  const int wr = (w >> 1) * 64, wc = (w & 1) * 64;

  const bf16* Ab = A + (size_t)m0 * 1024;
  const bf16* Bb = Bt + (size_t)n0 * 1024;

  f32x4 acc[4][4] = {};
  for (int k = 0; k < 16; ++k) {
    stage_tile<1024>(Ab + k * 64, 1024, smem);
    stage_tile<1024>(Bb + k * 64, 1024, smem + 128 * 64);
    __syncthreads();   // drains this tile's staging
    const bf16* As = smem;
    const bf16* Bs = smem + 128 * 64;
#pragma unroll
    for (int ks = 0; ks < 2; ++ks) {
      bf16x8 af[4], bfr[4];
#pragma unroll
      for (int i = 0; i < 4; ++i) af[i] = frag(As, wr + i * 16 + cc, ks * 4 + q4);
#pragma unroll
      for (int j = 0; j < 4; ++j) bfr[j] = frag(Bs, wc + j * 16 + cc, ks * 4 + q4);
      if (swapped) {
#pragma unroll
        for (int i = 0; i < 4; ++i)
#pragma unroll
          for (int j = 0; j < 4; ++j)
            acc[i][j] = __builtin_amdgcn_mfma_f32_16x16x32_bf16(bfr[j], af[i],
                                                                acc[i][j], 0, 0, 0);
      } else {
#pragma unroll
        for (int i = 0; i < 4; ++i)
#pragma unroll
          for (int j = 0; j < 4; ++j)
            acc[i][j] = __builtin_amdgcn_mfma_f32_16x16x32_bf16(af[i], bfr[j],
                                                                acc[i][j], 0, 0, 0);
      }
    }
    __syncthreads();   // all reads done before next iter's staging overwrites
  }
  // epilogue through smem (last barrier above makes the buffer free)
  bf16* eps = smem;
  const int b = m0 >> 11;   // whole block is one batch (128 | 2048)
  if (swapped) {
    // C^T: row(q4*4+r)=feature-local floc, col(cc)=token-local tloc.
#pragma unroll
    for (int i = 0; i < 4; ++i) {
      const int tloc = wr + i * 16 + cc;
#pragma unroll
      for (int j = 0; j < 4; ++j) {
        const int floc = wc + j * 16 + q4 * 4;
        const int R = ((floc >> 6) << 7) + tloc;
        const int cs = ((floc & 63) >> 3) ^ (tloc & 7);
        uint2 pv;
        pv.x = pk2(acc[i][j][0], acc[i][j][1]);
        pv.y = pk2(acc[i][j][2], acc[i][j][3]);
        *(uint2*)(eps + R * 64 + cs * 8 + (q4 & 1) * 4) = pv;
      }
    }
    __syncthreads();
    bf16* outN = isq ? qb : kb;
    const int h0 = n0 >> 6;
#pragma unroll
    for (int i = 0; i < 8; ++i) {
      const int p = i * 256 + tid;
      const int R = p >> 3, cg = p & 7;
      const int cs = cg ^ (R & 7);
      uint4 v = *(const uint4*)(eps + R * 64 + cs * 8);
      const int region = R >> 7, tloc = R & 127;
      const int n = (m0 & 2047) + tloc;
      *(uint4*)(outN + ((size_t)(b * 16 + h0 + region)) * 131072 +
                (size_t)n * 64 + cg * 8) = v;
    }
  } else {
    // normal: row(q4*4+r)=token-local (consecutive), col(cc)=feature-local.
#pragma unroll
    for (int i = 0; i < 4; ++i) {
      const int tloc = wr + i * 16 + q4 * 4;
#pragma unroll
      for (int j = 0; j < 4; ++j) {
        const int floc = wc + j * 16 + cc;
        const int cs = (tloc >> 3) ^ (floc & 7);
        uint2 pv;
        pv.x = pk2(acc[i][j][0], acc[i][j][1]);
        pv.y = pk2(acc[i][j][2], acc[i][j][3]);
        *(uint2*)(eps + floc * 128 + cs * 8 + (q4 & 1) * 4) = pv;
      }
    }
    __syncthreads();
    const int h0 = (n0 - 1024) >> 6;
#pragma unroll
    for (int i = 0; i < 8; ++i) {
      const int p = i * 256 + tid;
      const int R = p >> 4, cg = p & 15;
      const int cs = cg ^ (R & 7);
      uint4 v = *(const uint4*)(eps + R * 128 + cs * 8);
      const int region = R >> 6, din = R & 63;
      *(uint4*)(vtb + ((size_t)(b * 16 + h0 + region)) * 131072 +
                (size_t)din * 2048 + (m0 & 2047) + cg * 8) = v;
    }
  }
}

// ---------------------------------------------------------------------------
// Attention, S^T formulation with PERMUTED j-mapping (zero-shuffle transpose).
// S^T = K·Q^T with K rows permuted per tile: the K row loaded at A-operand
// lane cc of tile jt is row(jt,cc) = (jt>>1)*32 + (cc>>2)*8 + (jt&1)*4 + (cc&3).
// Under this bijection, lane (q4,cc)'s own exp2 outputs ARE its PV B-fragment.
// V uses identity j-mapping. O^T = V^T·P^T, col=q-row -> float4 stores.
// No max-subtract (scores ~N(0,1)); 1/rowsum at end. LDS = K/V tiles only.
//
// R0 structure: it=2, single-buffered, 4 blocks/CU. R1: dbuf+setprio regress.
// R2: swz -> 0 conflicts; it=4 kills occupancy. R4: pk2 = v_cvt_pk_bf16_f32
// (88.4->81). R5: XCD remap, FETCH 139.5->24.6MB. R6: rowsum-via-MFMA(ones)
// + KVBLK=128 (81->73.5us, MfmaUtil 44, VALU 41). FROZEN since R6.
__global__ __launch_bounds__(256, 4)
void attn(const bf16* __restrict__ Q, const bf16* __restrict__ Km,
          const bf16* __restrict__ VT, float* __restrict__ out) {
  __shared__ alignas(16) bf16 Ks[128 * 64];
  __shared__ alignas(16) bf16 VTs[2][64 * 64];
  const int tid = threadIdx.x, lane = tid & 63, w = tid >> 6;
  const int q4 = lane >> 4, cc = lane & 15;
  const int blk = blockIdx.x;
  const int bh  = (blk & 7) + 8 * (blk >> 7);
  const int it0 = ((blk >> 3) & 15) * 128;
  const bf16* Qg = Q + (size_t)bh * 131072 + (size_t)it0 * 64;
  const bf16* Kg = Km + (size_t)bh * 131072;
  const bf16* Vg = VT + (size_t)bh * 131072;

  // Q fragments direct from global (B-operand layout: n=cc, k=q4*8+j)
  bf16x8 qf[2][2];
#pragma unroll
  for (int it = 0; it < 2; ++it)
#pragma unroll
    for (int ks = 0; ks < 2; ++ks)
      qf[it][ks] = *(const bf16x8*)(Qg + (size_t)(w * 32 + it * 16 + cc) * 64 +
                                    ks * 32 + q4 * 8);

  // ones A-fragment for the rowsum MFMA (bf16 1.0 = 0x3F80)
  FragU onesf;
  onesf.i[0] = 0x3F803F80; onesf.i[1] = 0x3F803F80;
  onesf.i[2] = 0x3F803F80; onesf.i[3] = 0x3F803F80;

  // permuted K-row index for S^T tile jt at A-operand lane cc
  const int krow_lo = (cc >> 2) * 8 + (cc & 3);   // + (jt>>1)*32 + (jt&1)*4

  f32x4 o_t[4][2] = {};       // [dt][it], col = q-row
  f32x4 osum[2] = {};         // rowsum accum (all 4 regs identical)

  for (int j0 = 0; j0 < 2048; j0 += 128) {
    stage_tile<1024>(Kg + (size_t)j0 * 64, 64, Ks);
    stage_tile<512>(Vg + j0, 2048, VTs[0]);
    stage_tile<512>(Vg + j0 + 64, 2048, VTs[1]);
    __syncthreads();
#pragma unroll
    for (int h = 0; h < 2; ++h) {
      // S^T tiles: st[jt][it] = sum_ks mfma(A=K-frag(permuted rows), B=Q-frag)
      f32x4 st[4][2] = {};
#pragma unroll
      for (int ks = 0; ks < 2; ++ks) {
        bf16x8 kf[4];
#pragma unroll
        for (int jt = 0; jt < 4; ++jt)
          kf[jt] = frag(Ks, h * 64 + (jt >> 1) * 32 + (jt & 1) * 4 + krow_lo,
                        ks * 4 + q4);
#pragma unroll
        for (int jt = 0; jt < 4; ++jt)
#pragma unroll
          for (int it = 0; it < 2; ++it)
            st[jt][it] = __builtin_amdgcn_mfma_f32_16x16x32_bf16(kf[jt], qf[it][ks],
                                                                 st[jt][it], 0, 0, 0);
      }
      // exp2 + pack pairs (rowsum folded into the ones-MFMA below)
      int pk[4][2][2];
#pragma unroll
      for (int jt = 0; jt < 4; ++jt)
#pragma unroll
        for (int it = 0; it < 2; ++it) {
          float e0 = __builtin_amdgcn_exp2f(st[jt][it][0]);
          float e1 = __builtin_amdgcn_exp2f(st[jt][it][1]);
          float e2 = __builtin_amdgcn_exp2f(st[jt][it][2]);
          float e3 = __builtin_amdgcn_exp2f(st[jt][it][3]);
          pk[jt][it][0] = (int)pk2(e0, e1);
          pk[jt][it][1] = (int)pk2(e2, e3);
        }
      // O^T += V^T P^T ; P^T B-frag is the lane's OWN registers (permuted j)
#pragma unroll
      for (int ks = 0; ks < 2; ++ks) {
        bf16x8 vf[4];
#pragma unroll
        for (int dt = 0; dt < 4; ++dt)
          vf[dt] = frag(VTs[h], dt * 16 + cc, ks * 4 + q4);
#pragma unroll
        for (int it = 0; it < 2; ++it) {
          FragU fu;
          fu.i[0] = pk[2 * ks][it][0];
          fu.i[1] = pk[2 * ks][it][1];
          fu.i[2] = pk[2 * ks + 1][it][0];
          fu.i[3] = pk[2 * ks + 1][it][1];
#pragma unroll
          for (int dt = 0; dt < 4; ++dt)
            o_t[dt][it] = __builtin_amdgcn_mfma_f32_16x16x32_bf16(vf[dt], fu.v,
                                                                  o_t[dt][it], 0, 0, 0);
          osum[it] = __builtin_amdgcn_mfma_f32_16x16x32_bf16(onesf.v, fu.v,
                                                             osum[it], 0, 0, 0);
        }
      }
    }
    __syncthreads();
  }
  // osum[it][0] already = full sum_j P (MFMA reduced over K); no shuffles.
  float inv[2];
#pragma unroll
  for (int it = 0; it < 2; ++it) inv[it] = 1.0f / osum[it][0];
  const int b = bh >> 4, h = bh & 15;
#pragma unroll
  for (int it = 0; it < 2; ++it) {
    const int n = it0 + w * 32 + it * 16 + cc;
    const size_t base = ((size_t)b * 2048 + n) * 1024 + h * 64 + q4 * 4;
#pragma unroll
    for (int dt = 0; dt < 4; ++dt) {
      float4 val;
      val.x = o_t[dt][it][0] * inv[it];
      val.y = o_t[dt][it][1] * inv[it];
      val.z = o_t[dt][it][2] * inv[it];
      val.w = o_t[dt][it][3] * inv[it];
      *(float4*)(out + base + dt * 16) = val;
    }
  }
}

// ---------------------------------------------------------------------------
extern "C" void kernel_launch(void* const* d_in, const int* in_sizes, int n_in,
                              void* d_out, int out_size, void* d_ws, size_t ws_size,
                              hipStream_t stream) {
  const float* x   = (const float*)d_in[0];   // (4,2048,1024)
  const float* ctx = (const float*)d_in[1];   // (4,2048,1024)
  const float* Wq  = (const float*)d_in[2];   // (1024,1024)
  const float* Wkv = (const float*)d_in[3];   // (1024,2048)
  float* out = (float*)d_out;                 // (4,2048,1024) fp32
  char* ws = (char*)d_ws;
  bf16* xb   = (bf16*)(ws);                   // 8192x1024 bf16
  bf16* cb   = (bf16*)(ws + 16777216);        // 8192x1024 bf16
  bf16* wqt  = (bf16*)(ws + 33554432);        // 1024x1024 bf16 (W^T, pre-scaled)
  bf16* wkvt = (bf16*)(ws + 35651584);        // 2048x1024 bf16
  bf16* qb   = (bf16*)(ws + 39845888);        // (64,2048,64) bf16
  bf16* kb   = (bf16*)(ws + 56623104);        // (64,2048,64) bf16
  bf16* vtb  = (bf16*)(ws + 73400320);        // (64,64,2048) bf16

  prep<<<5120, 256, 0, stream>>>((const float4*)x, (ushort4*)xb,
                                 (const float4*)ctx, (ushort4*)cb,
                                 Wq, wqt, Wkv, wkvt);
  gemm_all<<<1536, 256, 0, stream>>>(xb, cb, wqt, wkvt, qb, kb, vtb);
  attn<<<1024, 256, 0, stream>>>(qb, kb, vtb, out);
}

// Round 11
// 297.059 us; speedup vs baseline: 2.2807x; 2.2807x over previous
//
#include <hip/hip_runtime.h>
#include <hip/hip_bf16.h>

using bf16 = __hip_bfloat16;
typedef __bf16 bf16x8 __attribute__((ext_vector_type(8)));
typedef float f32x4 __attribute__((ext_vector_type(4)));

#define DEV static __device__ __forceinline__

// ---------------------------------------------------------------------------
DEV void gld_lds16(const bf16* g, bf16* l) {
  __builtin_amdgcn_global_load_lds((__attribute__((address_space(1))) void*)g,
                                   (__attribute__((address_space(3))) void*)l,
                                   16, 0, 0);
}

// LDS chunk swizzle. Chosen so BOTH access patterns in play are >=8-spread:
//  - attn kf rows: base + (cc>>2)*8 + (cc&3)  -> bits r[1:0], r[3] vary
//  - attn vf / gemm rows: base16*k + cc       -> bits r[1:0], r[3] vary
// (R0 measured: old (r&7) swz -> SQ_LDS_BANK_CONFLICT == kf_reads*4 == 2^22
//  exactly; R2 measured: this swz -> 0 conflicts.)
DEV int swz(int r) { return (r & 3) | (((r >> 3) & 1) << 2); }

// Stage (NCHUNK/8) rows x 64 cols bf16 (row stride gs) into LDS, XOR-swizzled.
template<int NCHUNK>
DEV void stage_tile(const bf16* g, int gs, bf16* lds) {
  const int tid = threadIdx.x;
  const int w = tid >> 6, lane = tid & 63;
#pragma unroll
  for (int i = 0; i < NCHUNK / 256; ++i) {
    const int pb = i * 256 + w * 64;   // wave-uniform chunk base
    const int p  = pb + lane;
    const int r  = p >> 3;
    const int c  = (p & 7) ^ swz(r);
    gld_lds16(g + r * gs + c * 8, lds + pb * 8);
  }
}

DEV bf16x8 frag(const bf16* lds, int row, int cchunk) {
  const int p = row * 8 + (cchunk ^ swz(row));
  return *(const bf16x8*)(lds + p * 8);
}

// Packed f32x2 -> bf16x2 in ONE instruction (RNE). hip_bf16's
// __float2bfloat16 lowers to a multi-instr software-RNE sequence; at
// 2.68e8 conversions in attn that was ~7us of VALU (R4: 88.4->81us).
DEV unsigned pk2(float a, float b) {
  unsigned r;
  asm("v_cvt_pk_bf16_f32 %0, %1, %2" : "=v"(r) : "v"(a), "v"(b));
  return r;
}

union FragU { int i[4]; bf16x8 v; };

// ---------------------------------------------------------------------------
// prep: fp32->bf16 convert (blocks [0,2048)) + W transposes (blocks [2048,5120))
// Wq transpose folds scale = 0.125 * log2(e) so attention uses HW exp2.
// (R9 lesson: fusing the convert into gemm's staging reg-path serializes
// global->cvt->ds_write before the barrier -> gemm 66->127us. Keep prep.)
__global__ void prep(const float4* __restrict__ x, ushort4* __restrict__ xb,
                     const float4* __restrict__ ctx, ushort4* __restrict__ cb,
                     const float* __restrict__ wq, bf16* __restrict__ wqt,
                     const float* __restrict__ wkv, bf16* __restrict__ wkvt) {
  __shared__ float t[32][33];
  const int tid = threadIdx.x;
  if (blockIdx.x < 2048) {
    int i = blockIdx.x * 256 + tid;
    const int stride = 2048 * 256;
#pragma unroll
    for (int s = 0; s < 4; ++s, i += stride) {
      float4 a = x[i];
      float4 b = ctx[i];
      union { ushort4 u; unsigned v[2]; } oa, ob;
      oa.v[0] = pk2(a.x, a.y); oa.v[1] = pk2(a.z, a.w);
      ob.v[0] = pk2(b.x, b.y); ob.v[1] = pk2(b.z, b.w);
      xb[i] = oa.u;
      cb[i] = ob.u;
    }
    return;
  }
  const int tb = blockIdx.x - 2048;      // 3072 = 96 x 32
  int bx = tb % 96;
  const int by = tb / 96;
  const float* in; bf16* out; int N; float scale;
  if (bx < 32) { in = wq;  out = wqt;  N = 1024; scale = 0.18033688011112042f; }
  else         { in = wkv; out = wkvt; N = 2048; scale = 1.0f; bx -= 32; }
  const int k0 = by * 32, n0 = bx * 32;
  const int tx = tid & 31, ty = tid >> 5;  // 32 x 8
#pragma unroll
  for (int s = 0; s < 4; ++s)
    t[ty + 8 * s][tx] = in[(size_t)(k0 + ty + 8 * s) * N + n0 + tx];
  __syncthreads();
#pragma unroll
  for (int s = 0; s < 4; ++s)
    out[(size_t)(n0 + ty + 8 * s) * 1024 + k0 + tx] =
        __float2bfloat16(t[tx][ty + 8 * s] * scale);
}

// ---------------------------------------------------------------------------
// Merged q/kv GEMM. R11: single-buffered 32KB LDS, __launch_bounds__(256,3).
// R10's bounds(256,4) capped unified regs at 128/wave but the kernel needs
// ~100 arch VGPR + 64 acc AGPR = 164 -> compiler SPILLED the accumulators
// (measured: WRITE_SIZE 1.1GB scratch, MfmaUtil 4%, gemm 516us). bounds=3
// gives 2048/3 ~= 170 regs: fits, 3 blocks/CU (LDS 96KB), 12 waves/CU --
// 1.5x the TLP of R7's dbuf-at-2-blocks (R9 measured that config
// latency-bound: Occupancy 21%, both pipes <16%).
// R7: XCD-aware M-stripe mapping (XCD c owns m-panels [c*8,c*8+8), n fastest).
// blocks [0,512) = q, [512,1536) = kv.
// q/k blocks: SWAPPED operands -> C^T. v blocks: normal.
// Epilogue reuses the 32KB buffer (both tile layouts are exactly 32KB).
__global__ __launch_bounds__(256, 3)
void gemm_all(const bf16* __restrict__ xb, const bf16* __restrict__ cb,
              const bf16* __restrict__ wqt, const bf16* __restrict__ wkvt,
              bf16* __restrict__ qb, bf16* __restrict__ kb, bf16* __restrict__ vtb) {
  __shared__ alignas(16) bf16 smem[128 * 64 * 2];   // 32 KB: A tile + B tile
  const int id = blockIdx.x;
  const bool isq = id < 512;
  const bf16* A; const bf16* Bt; int m0, n0;
  if (isq) {
    A = xb; Bt = wqt;
    const int c = id & 7, j = id >> 3;         // j in [0,64)
    n0 = (j & 7) * 128;
    m0 = (c * 8 + (j >> 3)) * 128;             // m-index in [0,64)
  } else {
    const int id2 = id - 512;
    A = cb; Bt = wkvt;
    const int c = id2 & 7, j = id2 >> 3;       // j in [0,128)
    n0 = (j & 15) * 128;
    m0 = (c * 8 + (j >> 4)) * 128;             // m-index in [0,64)
  }
  const bool swapped = isq || (n0 < 1024);   // q and k blocks
  const int tid = threadIdx.x, lane = tid & 63, w = tid >> 6;
  const int q4 = lane >> 4, cc = lane & 15;
  const int wr = (w >> 1) * 64, wc = (w & 1) * 64;

  const bf16* Ab = A + (size_t)m0 * 1024;
  const bf16* Bb = Bt + (size_t)n0 * 1024;

  f32x4 acc[4][4] = {};
  for (int k = 0; k < 16; ++k) {
    stage_tile<1024>(Ab + k * 64, 1024, smem);
    stage_tile<1024>(Bb + k * 64, 1024, smem + 128 * 64);
    __syncthreads();   // drains this tile's staging
    const bf16* As = smem;
    const bf16* Bs = smem + 128 * 64;
#pragma unroll
    for (int ks = 0; ks < 2; ++ks) {
      bf16x8 af[4], bfr[4];
#pragma unroll
      for (int i = 0; i < 4; ++i) af[i] = frag(As, wr + i * 16 + cc, ks * 4 + q4);
#pragma unroll
      for (int j = 0; j < 4; ++j) bfr[j] = frag(Bs, wc + j * 16 + cc, ks * 4 + q4);
      if (swapped) {
#pragma unroll
        for (int i = 0; i < 4; ++i)
#pragma unroll
          for (int j = 0; j < 4; ++j)
            acc[i][j] = __builtin_amdgcn_mfma_f32_16x16x32_bf16(bfr[j], af[i],
                                                                acc[i][j], 0, 0, 0);
      } else {
#pragma unroll
        for (int i = 0; i < 4; ++i)
#pragma unroll
          for (int j = 0; j < 4; ++j)
            acc[i][j] = __builtin_amdgcn_mfma_f32_16x16x32_bf16(af[i], bfr[j],
                                                                acc[i][j], 0, 0, 0);
      }
    }
    __syncthreads();   // all reads done before next iter's staging overwrites
  }
  // epilogue through smem (last barrier above makes the buffer free)
  bf16* eps = smem;
  const int b = m0 >> 11;   // whole block is one batch (128 | 2048)
  if (swapped) {
    // C^T: row(q4*4+r)=feature-local floc, col(cc)=token-local tloc.
#pragma unroll
    for (int i = 0; i < 4; ++i) {
      const int tloc = wr + i * 16 + cc;
#pragma unroll
      for (int j = 0; j < 4; ++j) {
        const int floc = wc + j * 16 + q4 * 4;
        const int R = ((floc >> 6) << 7) + tloc;
        const int cs = ((floc & 63) >> 3) ^ (tloc & 7);
        uint2 pv;
        pv.x = pk2(acc[i][j][0], acc[i][j][1]);
        pv.y = pk2(acc[i][j][2], acc[i][j][3]);
        *(uint2*)(eps + R * 64 + cs * 8 + (q4 & 1) * 4) = pv;
      }
    }
    __syncthreads();
    bf16* outN = isq ? qb : kb;
    const int h0 = n0 >> 6;
#pragma unroll
    for (int i = 0; i < 8; ++i) {
      const int p = i * 256 + tid;
      const int R = p >> 3, cg = p & 7;
      const int cs = cg ^ (R & 7);
      uint4 v = *(const uint4*)(eps + R * 64 + cs * 8);
      const int region = R >> 7, tloc = R & 127;
      const int n = (m0 & 2047) + tloc;
      *(uint4*)(outN + ((size_t)(b * 16 + h0 + region)) * 131072 +
                (size_t)n * 64 + cg * 8) = v;
    }
  } else {
    // normal: row(q4*4+r)=token-local (consecutive), col(cc)=feature-local.
#pragma unroll
    for (int i = 0; i < 4; ++i) {
      const int tloc = wr + i * 16 + q4 * 4;
#pragma unroll
      for (int j = 0; j < 4; ++j) {
        const int floc = wc + j * 16 + cc;
        const int cs = (tloc >> 3) ^ (floc & 7);
        uint2 pv;
        pv.x = pk2(acc[i][j][0], acc[i][j][1]);
        pv.y = pk2(acc[i][j][2], acc[i][j][3]);
        *(uint2*)(eps + floc * 128 + cs * 8 + (q4 & 1) * 4) = pv;
      }
    }
    __syncthreads();
    const int h0 = (n0 - 1024) >> 6;
#pragma unroll
    for (int i = 0; i < 8; ++i) {
      const int p = i * 256 + tid;
      const int R = p >> 4, cg = p & 15;
      const int cs = cg ^ (R & 7);
      uint4 v = *(const uint4*)(eps + R * 128 + cs * 8);
      const int region = R >> 6, din = R & 63;
      *(uint4*)(vtb + ((size_t)(b * 16 + h0 + region)) * 131072 +
                (size_t)din * 2048 + (m0 & 2047) + cg * 8) = v;
    }
  }
}

// ---------------------------------------------------------------------------
// Attention, S^T formulation with PERMUTED j-mapping (zero-shuffle transpose).
// S^T = K·Q^T with K rows permuted per tile: the K row loaded at A-operand
// lane cc of tile jt is row(jt,cc) = (jt>>1)*32 + (cc>>2)*8 + (jt&1)*4 + (cc&3).
// Under this bijection, lane (q4,cc)'s own exp2 outputs ARE its PV B-fragment.
// V uses identity j-mapping. O^T = V^T·P^T, col=q-row -> float4 stores.
// No max-subtract (scores ~N(0,1)); 1/rowsum at end. LDS = K/V tiles only.
//
// R0 structure: it=2, single-buffered, 4 blocks/CU. R1: dbuf+setprio regress.
// R2: swz -> 0 conflicts; it=4 kills occupancy. R4: pk2 = v_cvt_pk_bf16_f32
// (88.4->81). R5: XCD remap, FETCH 139.5->24.6MB. R6: rowsum-via-MFMA(ones)
// + KVBLK=128 (81->73.5us, MfmaUtil 44, VALU 41). FROZEN since R6.
__global__ __launch_bounds__(256, 4)
void attn(const bf16* __restrict__ Q, const bf16* __restrict__ Km,
          const bf16* __restrict__ VT, float* __restrict__ out) {
  __shared__ alignas(16) bf16 Ks[128 * 64];
  __shared__ alignas(16) bf16 VTs[2][64 * 64];
  const int tid = threadIdx.x, lane = tid & 63, w = tid >> 6;
  const int q4 = lane >> 4, cc = lane & 15;
  const int blk = blockIdx.x;
  const int bh  = (blk & 7) + 8 * (blk >> 7);
  const int it0 = ((blk >> 3) & 15) * 128;
  const bf16* Qg = Q + (size_t)bh * 131072 + (size_t)it0 * 64;
  const bf16* Kg = Km + (size_t)bh * 131072;
  const bf16* Vg = VT + (size_t)bh * 131072;

  // Q fragments direct from global (B-operand layout: n=cc, k=q4*8+j)
  bf16x8 qf[2][2];
#pragma unroll
  for (int it = 0; it < 2; ++it)
#pragma unroll
    for (int ks = 0; ks < 2; ++ks)
      qf[it][ks] = *(const bf16x8*)(Qg + (size_t)(w * 32 + it * 16 + cc) * 64 +
                                    ks * 32 + q4 * 8);

  // ones A-fragment for the rowsum MFMA (bf16 1.0 = 0x3F80)
  FragU onesf;
  onesf.i[0] = 0x3F803F80; onesf.i[1] = 0x3F803F80;
  onesf.i[2] = 0x3F803F80; onesf.i[3] = 0x3F803F80;

  // permuted K-row index for S^T tile jt at A-operand lane cc
  const int krow_lo = (cc >> 2) * 8 + (cc & 3);   // + (jt>>1)*32 + (jt&1)*4

  f32x4 o_t[4][2] = {};       // [dt][it], col = q-row
  f32x4 osum[2] = {};         // rowsum accum (all 4 regs identical)

  for (int j0 = 0; j0 < 2048; j0 += 128) {
    stage_tile<1024>(Kg + (size_t)j0 * 64, 64, Ks);
    stage_tile<512>(Vg + j0, 2048, VTs[0]);
    stage_tile<512>(Vg + j0 + 64, 2048, VTs[1]);
    __syncthreads();
#pragma unroll
    for (int h = 0; h < 2; ++h) {
      // S^T tiles: st[jt][it] = sum_ks mfma(A=K-frag(permuted rows), B=Q-frag)
      f32x4 st[4][2] = {};
#pragma unroll
      for (int ks = 0; ks < 2; ++ks) {
        bf16x8 kf[4];
#pragma unroll
        for (int jt = 0; jt < 4; ++jt)
          kf[jt] = frag(Ks, h * 64 + (jt >> 1) * 32 + (jt & 1) * 4 + krow_lo,
                        ks * 4 + q4);
#pragma unroll
        for (int jt = 0; jt < 4; ++jt)
#pragma unroll
          for (int it = 0; it < 2; ++it)
            st[jt][it] = __builtin_amdgcn_mfma_f32_16x16x32_bf16(kf[jt], qf[it][ks],
                                                                 st[jt][it], 0, 0, 0);
      }
      // exp2 + pack pairs (rowsum folded into the ones-MFMA below)
      int pk[4][2][2];
#pragma unroll
      for (int jt = 0; jt < 4; ++jt)
#pragma unroll
        for (int it = 0; it < 2; ++it) {
          float e0 = __builtin_amdgcn_exp2f(st[jt][it][0]);
          float e1 = __builtin_amdgcn_exp2f(st[jt][it][1]);
          float e2 = __builtin_amdgcn_exp2f(st[jt][it][2]);
          float e3 = __builtin_amdgcn_exp2f(st[jt][it][3]);
          pk[jt][it][0] = (int)pk2(e0, e1);
          pk[jt][it][1] = (int)pk2(e2, e3);
        }
      // O^T += V^T P^T ; P^T B-frag is the lane's OWN registers (permuted j)
#pragma unroll
      for (int ks = 0; ks < 2; ++ks) {
        bf16x8 vf[4];
#pragma unroll
        for (int dt = 0; dt < 4; ++dt)
          vf[dt] = frag(VTs[h], dt * 16 + cc, ks * 4 + q4);
#pragma unroll
        for (int it = 0; it < 2; ++it) {
          FragU fu;
          fu.i[0] = pk[2 * ks][it][0];
          fu.i[1] = pk[2 * ks][it][1];
          fu.i[2] = pk[2 * ks + 1][it][0];
          fu.i[3] = pk[2 * ks + 1][it][1];
#pragma unroll
          for (int dt = 0; dt < 4; ++dt)
            o_t[dt][it] = __builtin_amdgcn_mfma_f32_16x16x32_bf16(vf[dt], fu.v,
                                                                  o_t[dt][it], 0, 0, 0);
          osum[it] = __builtin_amdgcn_mfma_f32_16x16x32_bf16(onesf.v, fu.v,
                                                             osum[it], 0, 0, 0);
        }
      }
    }
    __syncthreads();
  }
  // osum[it][0] already = full sum_j P (MFMA reduced over K); no shuffles.
  float inv[2];
#pragma unroll
  for (int it = 0; it < 2; ++it) inv[it] = 1.0f / osum[it][0];
  const int b = bh >> 4, h = bh & 15;
#pragma unroll
  for (int it = 0; it < 2; ++it) {
    const int n = it0 + w * 32 + it * 16 + cc;
    const size_t base = ((size_t)b * 2048 + n) * 1024 + h * 64 + q4 * 4;
#pragma unroll
    for (int dt = 0; dt < 4; ++dt) {
      float4 val;
      val.x = o_t[dt][it][0] * inv[it];
      val.y = o_t[dt][it][1] * inv[it];
      val.z = o_t[dt][it][2] * inv[it];
      val.w = o_t[dt][it][3] * inv[it];
      *(float4*)(out + base + dt * 16) = val;
    }
  }
}

// ---------------------------------------------------------------------------
extern "C" void kernel_launch(void* const* d_in, const int* in_sizes, int n_in,
                              void* d_out, int out_size, void* d_ws, size_t ws_size,
                              hipStream_t stream) {
  const float* x   = (const float*)d_in[0];   // (4,2048,1024)
  const float* ctx = (const float*)d_in[1];   // (4,2048,1024)
  const float* Wq  = (const float*)d_in[2];   // (1024,1024)
  const float* Wkv = (const float*)d_in[3];   // (1024,2048)
  float* out = (float*)d_out;                 // (4,2048,1024) fp32
  char* ws = (char*)d_ws;
  bf16* xb   = (bf16*)(ws);                   // 8192x1024 bf16
  bf16* cb   = (bf16*)(ws + 16777216);        // 8192x1024 bf16
  bf16* wqt  = (bf16*)(ws + 33554432);        // 1024x1024 bf16 (W^T, pre-scaled)
  bf16* wkvt = (bf16*)(ws + 35651584);        // 2048x1024 bf16
  bf16* qb   = (bf16*)(ws + 39845888);        // (64,2048,64) bf16
  bf16* kb   = (bf16*)(ws + 56623104);        // (64,2048,64) bf16
  bf16* vtb  = (bf16*)(ws + 73400320);        // (64,64,2048) bf16

  prep<<<5120, 256, 0, stream>>>((const float4*)x, (ushort4*)xb,
                                 (const float4*)ctx, (ushort4*)cb,
                                 Wq, wqt, Wkv, wkvt);
  gemm_all<<<1536, 256, 0, stream>>>(xb, cb, wqt, wkvt, qb, kb, vtb);
  attn<<<1024, 256, 0, stream>>>(qb, kb, vtb, out);
}

// Round 12
// 241.831 us; speedup vs baseline: 2.8015x; 1.2284x over previous
//
#include <hip/hip_runtime.h>
#include <hip/hip_bf16.h>

using bf16 = __hip_bfloat16;
typedef __bf16 bf16x8 __attribute__((ext_vector_type(8)));
typedef float f32x4 __attribute__((ext_vector_type(4)));

#define DEV static __device__ __forceinline__

// ---------------------------------------------------------------------------
DEV void gld_lds16(const bf16* g, bf16* l) {
  __builtin_amdgcn_global_load_lds((__attribute__((address_space(1))) void*)g,
                                   (__attribute__((address_space(3))) void*)l,
                                   16, 0, 0);
}

// LDS chunk swizzle. Chosen so BOTH access patterns in play are >=8-spread:
//  - attn kf rows: base + (cc>>2)*8 + (cc&3)  -> bits r[1:0], r[3] vary
//  - attn vf / gemm rows: base16*k + cc       -> bits r[1:0], r[3] vary
// (R0 measured: old (r&7) swz -> SQ_LDS_BANK_CONFLICT == kf_reads*4 == 2^22
//  exactly; R2 measured: this swz -> 0 conflicts.)
DEV int swz(int r) { return (r & 3) | (((r >> 3) & 1) << 2); }

// Stage (NCHUNK/8) rows x 64 cols bf16 (row stride gs) into LDS, XOR-swizzled.
template<int NCHUNK>
DEV void stage_tile(const bf16* g, int gs, bf16* lds) {
  const int tid = threadIdx.x;
  const int w = tid >> 6, lane = tid & 63;
#pragma unroll
  for (int i = 0; i < NCHUNK / 256; ++i) {
    const int pb = i * 256 + w * 64;   // wave-uniform chunk base
    const int p  = pb + lane;
    const int r  = p >> 3;
    const int c  = (p & 7) ^ swz(r);
    gld_lds16(g + r * gs + c * 8, lds + pb * 8);
  }
}

DEV bf16x8 frag(const bf16* lds, int row, int cchunk) {
  const int p = row * 8 + (cchunk ^ swz(row));
  return *(const bf16x8*)(lds + p * 8);
}

// Packed f32x2 -> bf16x2 in ONE instruction (RNE). hip_bf16's
// __float2bfloat16 lowers to a multi-instr software-RNE sequence; at
// 2.68e8 conversions in attn that was ~7us of VALU (R4: 88.4->81us).
DEV unsigned pk2(float a, float b) {
  unsigned r;
  asm("v_cvt_pk_bf16_f32 %0, %1, %2" : "=v"(r) : "v"(a), "v"(b));
  return r;
}

union FragU { int i[4]; bf16x8 v; };

// ---------------------------------------------------------------------------
// prep: fp32->bf16 convert (blocks [0,2048)) + W transposes (blocks [2048,5120))
// Wq transpose folds scale = 0.125 * log2(e) so attention uses HW exp2.
// (R9 lesson: fusing the convert into gemm's staging reg-path serializes
// global->cvt->ds_write before the barrier -> gemm 66->127us. Keep prep.)
__global__ void prep(const float4* __restrict__ x, ushort4* __restrict__ xb,
                     const float4* __restrict__ ctx, ushort4* __restrict__ cb,
                     const float* __restrict__ wq, bf16* __restrict__ wqt,
                     const float* __restrict__ wkv, bf16* __restrict__ wkvt) {
  __shared__ float t[32][33];
  const int tid = threadIdx.x;
  if (blockIdx.x < 2048) {
    int i = blockIdx.x * 256 + tid;
    const int stride = 2048 * 256;
#pragma unroll
    for (int s = 0; s < 4; ++s, i += stride) {
      float4 a = x[i];
      float4 b = ctx[i];
      union { ushort4 u; unsigned v[2]; } oa, ob;
      oa.v[0] = pk2(a.x, a.y); oa.v[1] = pk2(a.z, a.w);
      ob.v[0] = pk2(b.x, b.y); ob.v[1] = pk2(b.z, b.w);
      xb[i] = oa.u;
      cb[i] = ob.u;
    }
    return;
  }
  const int tb = blockIdx.x - 2048;      // 3072 = 96 x 32
  int bx = tb % 96;
  const int by = tb / 96;
  const float* in; bf16* out; int N; float scale;
  if (bx < 32) { in = wq;  out = wqt;  N = 1024; scale = 0.18033688011112042f; }
  else         { in = wkv; out = wkvt; N = 2048; scale = 1.0f; bx -= 32; }
  const int k0 = by * 32, n0 = bx * 32;
  const int tx = tid & 31, ty = tid >> 5;  // 32 x 8
#pragma unroll
  for (int s = 0; s < 4; ++s)
    t[ty + 8 * s][tx] = in[(size_t)(k0 + ty + 8 * s) * N + n0 + tx];
  __syncthreads();
#pragma unroll
  for (int s = 0; s < 4; ++s)
    out[(size_t)(n0 + ty + 8 * s) * 1024 + k0 + tx] =
        __float2bfloat16(t[tx][ty + 8 * s] * scale);
}

// ---------------------------------------------------------------------------
// Merged q/kv GEMM, DOUBLE-BUFFERED staging: 2 x (As+Bs) = 64 KB LDS,
// ONE barrier per k-iter; prefetch of k+1 flies during compute of k.
// R12: REVERT to this exact R7 config -- the best-measured gemm. Ledger:
// dbuf@2blk ~60-66us (this) | single@3blk 110us (R11: latency-exposed,
// A/B stream from L3/HBM ~600-900cy vs attn's L2-hit 200cy) | single@4blk
// 516us (R10: acc AGPRs spilled at 128-reg budget; WRITE 1.1GB) |
// fused-reg 127us (R9: global->cvt->ds_write serialized pre-barrier).
// R7: XCD-aware M-stripe mapping (XCD c owns m-panels [c*8,c*8+8), n fastest).
// blocks [0,512) = q, [512,1536) = kv.
// q/k blocks: SWAPPED operands -> C^T. v blocks: normal.
__global__ __launch_bounds__(256, 2)
void gemm_all(const bf16* __restrict__ xb, const bf16* __restrict__ cb,
              const bf16* __restrict__ wqt, const bf16* __restrict__ wkvt,
              bf16* __restrict__ qb, bf16* __restrict__ kb, bf16* __restrict__ vtb) {
  __shared__ alignas(16) bf16 smem[2][128 * 64 * 2];   // 64 KB
  const int id = blockIdx.x;
  const bool isq = id < 512;
  const bf16* A; const bf16* Bt; int m0, n0;
  if (isq) {
    A = xb; Bt = wqt;
    const int c = id & 7, j = id >> 3;         // j in [0,64)
    n0 = (j & 7) * 128;
    m0 = (c * 8 + (j >> 3)) * 128;             // m-index in [0,64)
  } else {
    const int id2 = id - 512;
    A = cb; Bt = wkvt;
    const int c = id2 & 7, j = id2 >> 3;       // j in [0,128)
    n0 = (j & 15) * 128;
    m0 = (c * 8 + (j >> 4)) * 128;             // m-index in [0,64)
  }
  const bool swapped = isq || (n0 < 1024);   // q and k blocks
  const int tid = threadIdx.x, lane = tid & 63, w = tid >> 6;
  const int q4 = lane >> 4, cc = lane & 15;
  const int wr = (w >> 1) * 64, wc = (w & 1) * 64;

  const bf16* Ab = A + (size_t)m0 * 1024;
  const bf16* Bb = Bt + (size_t)n0 * 1024;

  stage_tile<1024>(Ab, 1024, smem[0]);
  stage_tile<1024>(Bb, 1024, smem[0] + 128 * 64);

  f32x4 acc[4][4] = {};
  for (int k = 0; k < 16; ++k) {
    __syncthreads();   // drains staging of buf[k&1]; prior ds_reads already landed
    if (k + 1 < 16) {
      bf16* nb = smem[(k + 1) & 1];
      stage_tile<1024>(Ab + (k + 1) * 64, 1024, nb);
      stage_tile<1024>(Bb + (k + 1) * 64, 1024, nb + 128 * 64);
    }
    const bf16* As = smem[k & 1];
    const bf16* Bs = As + 128 * 64;
#pragma unroll
    for (int ks = 0; ks < 2; ++ks) {
      bf16x8 af[4], bfr[4];
#pragma unroll
      for (int i = 0; i < 4; ++i) af[i] = frag(As, wr + i * 16 + cc, ks * 4 + q4);
#pragma unroll
      for (int j = 0; j < 4; ++j) bfr[j] = frag(Bs, wc + j * 16 + cc, ks * 4 + q4);
      if (swapped) {
#pragma unroll
        for (int i = 0; i < 4; ++i)
#pragma unroll
          for (int j = 0; j < 4; ++j)
            acc[i][j] = __builtin_amdgcn_mfma_f32_16x16x32_bf16(bfr[j], af[i],
                                                                acc[i][j], 0, 0, 0);
      } else {
#pragma unroll
        for (int i = 0; i < 4; ++i)
#pragma unroll
          for (int j = 0; j < 4; ++j)
            acc[i][j] = __builtin_amdgcn_mfma_f32_16x16x32_bf16(af[i], bfr[j],
                                                                acc[i][j], 0, 0, 0);
      }
    }
  }
  // epilogue through smem[0] (32 KB region; last compute used smem[1])
  bf16* eps = smem[0];
  const int b = m0 >> 11;   // whole block is one batch (128 | 2048)
  if (swapped) {
    // C^T: row(q4*4+r)=feature-local floc, col(cc)=token-local tloc.
#pragma unroll
    for (int i = 0; i < 4; ++i) {
      const int tloc = wr + i * 16 + cc;
#pragma unroll
      for (int j = 0; j < 4; ++j) {
        const int floc = wc + j * 16 + q4 * 4;
        const int R = ((floc >> 6) << 7) + tloc;
        const int cs = ((floc & 63) >> 3) ^ (tloc & 7);
        uint2 pv;
        pv.x = pk2(acc[i][j][0], acc[i][j][1]);
        pv.y = pk2(acc[i][j][2], acc[i][j][3]);
        *(uint2*)(eps + R * 64 + cs * 8 + (q4 & 1) * 4) = pv;
      }
    }
    __syncthreads();
    bf16* outN = isq ? qb : kb;
    const int h0 = n0 >> 6;
#pragma unroll
    for (int i = 0; i < 8; ++i) {
      const int p = i * 256 + tid;
      const int R = p >> 3, cg = p & 7;
      const int cs = cg ^ (R & 7);
      uint4 v = *(const uint4*)(eps + R * 64 + cs * 8);
      const int region = R >> 7, tloc = R & 127;
      const int n = (m0 & 2047) + tloc;
      *(uint4*)(outN + ((size_t)(b * 16 + h0 + region)) * 131072 +
                (size_t)n * 64 + cg * 8) = v;
    }
  } else {
    // normal: row(q4*4+r)=token-local (consecutive), col(cc)=feature-local.
#pragma unroll
    for (int i = 0; i < 4; ++i) {
      const int tloc = wr + i * 16 + q4 * 4;
#pragma unroll
      for (int j = 0; j < 4; ++j) {
        const int floc = wc + j * 16 + cc;
        const int cs = (tloc >> 3) ^ (floc & 7);
        uint2 pv;
        pv.x = pk2(acc[i][j][0], acc[i][j][1]);
        pv.y = pk2(acc[i][j][2], acc[i][j][3]);
        *(uint2*)(eps + floc * 128 + cs * 8 + (q4 & 1) * 4) = pv;
      }
    }
    __syncthreads();
    const int h0 = (n0 - 1024) >> 6;
#pragma unroll
    for (int i = 0; i < 8; ++i) {
      const int p = i * 256 + tid;
      const int R = p >> 4, cg = p & 15;
      const int cs = cg ^ (R & 7);
      uint4 v = *(const uint4*)(eps + R * 128 + cs * 8);
      const int region = R >> 6, din = R & 63;
      *(uint4*)(vtb + ((size_t)(b * 16 + h0 + region)) * 131072 +
                (size_t)din * 2048 + (m0 & 2047) + cg * 8) = v;
    }
  }
}

// ---------------------------------------------------------------------------
// Attention, S^T formulation with PERMUTED j-mapping (zero-shuffle transpose).
// S^T = K·Q^T with K rows permuted per tile: the K row loaded at A-operand
// lane cc of tile jt is row(jt,cc) = (jt>>1)*32 + (cc>>2)*8 + (jt&1)*4 + (cc&3).
// Under this bijection, lane (q4,cc)'s own exp2 outputs ARE its PV B-fragment.
// V uses identity j-mapping. O^T = V^T·P^T, col=q-row -> float4 stores.
// No max-subtract (scores ~N(0,1)); 1/rowsum at end. LDS = K/V tiles only.
//
// R0 structure: it=2, single-buffered, 4 blocks/CU. R1: dbuf+setprio regress.
// R2: swz -> 0 conflicts; it=4 kills occupancy. R4: pk2 = v_cvt_pk_bf16_f32
// (88.4->81). R5: XCD remap, FETCH 139.5->24.6MB. R6: rowsum-via-MFMA(ones)
// + KVBLK=128 (81->73.5us, MfmaUtil 44, VALU 41). FROZEN since R6.
__global__ __launch_bounds__(256, 4)
void attn(const bf16* __restrict__ Q, const bf16* __restrict__ Km,
          const bf16* __restrict__ VT, float* __restrict__ out) {
  __shared__ alignas(16) bf16 Ks[128 * 64];
  __shared__ alignas(16) bf16 VTs[2][64 * 64];
  const int tid = threadIdx.x, lane = tid & 63, w = tid >> 6;
  const int q4 = lane >> 4, cc = lane & 15;
  const int blk = blockIdx.x;
  const int bh  = (blk & 7) + 8 * (blk >> 7);
  const int it0 = ((blk >> 3) & 15) * 128;
  const bf16* Qg = Q + (size_t)bh * 131072 + (size_t)it0 * 64;
  const bf16* Kg = Km + (size_t)bh * 131072;
  const bf16* Vg = VT + (size_t)bh * 131072;

  // Q fragments direct from global (B-operand layout: n=cc, k=q4*8+j)
  bf16x8 qf[2][2];
#pragma unroll
  for (int it = 0; it < 2; ++it)
#pragma unroll
    for (int ks = 0; ks < 2; ++ks)
      qf[it][ks] = *(const bf16x8*)(Qg + (size_t)(w * 32 + it * 16 + cc) * 64 +
                                    ks * 32 + q4 * 8);

  // ones A-fragment for the rowsum MFMA (bf16 1.0 = 0x3F80)
  FragU onesf;
  onesf.i[0] = 0x3F803F80; onesf.i[1] = 0x3F803F80;
  onesf.i[2] = 0x3F803F80; onesf.i[3] = 0x3F803F80;

  // permuted K-row index for S^T tile jt at A-operand lane cc
  const int krow_lo = (cc >> 2) * 8 + (cc & 3);   // + (jt>>1)*32 + (jt&1)*4

  f32x4 o_t[4][2] = {};       // [dt][it], col = q-row
  f32x4 osum[2] = {};         // rowsum accum (all 4 regs identical)

  for (int j0 = 0; j0 < 2048; j0 += 128) {
    stage_tile<1024>(Kg + (size_t)j0 * 64, 64, Ks);
    stage_tile<512>(Vg + j0, 2048, VTs[0]);
    stage_tile<512>(Vg + j0 + 64, 2048, VTs[1]);
    __syncthreads();
#pragma unroll
    for (int h = 0; h < 2; ++h) {
      // S^T tiles: st[jt][it] = sum_ks mfma(A=K-frag(permuted rows), B=Q-frag)
      f32x4 st[4][2] = {};
#pragma unroll
      for (int ks = 0; ks < 2; ++ks) {
        bf16x8 kf[4];
#pragma unroll
        for (int jt = 0; jt < 4; ++jt)
          kf[jt] = frag(Ks, h * 64 + (jt >> 1) * 32 + (jt & 1) * 4 + krow_lo,
                        ks * 4 + q4);
#pragma unroll
        for (int jt = 0; jt < 4; ++jt)
#pragma unroll
          for (int it = 0; it < 2; ++it)
            st[jt][it] = __builtin_amdgcn_mfma_f32_16x16x32_bf16(kf[jt], qf[it][ks],
                                                                 st[jt][it], 0, 0, 0);
      }
      // exp2 + pack pairs (rowsum folded into the ones-MFMA below)
      int pk[4][2][2];
#pragma unroll
      for (int jt = 0; jt < 4; ++jt)
#pragma unroll
        for (int it = 0; it < 2; ++it) {
          float e0 = __builtin_amdgcn_exp2f(st[jt][it][0]);
          float e1 = __builtin_amdgcn_exp2f(st[jt][it][1]);
          float e2 = __builtin_amdgcn_exp2f(st[jt][it][2]);
          float e3 = __builtin_amdgcn_exp2f(st[jt][it][3]);
          pk[jt][it][0] = (int)pk2(e0, e1);
          pk[jt][it][1] = (int)pk2(e2, e3);
        }
      // O^T += V^T P^T ; P^T B-frag is the lane's OWN registers (permuted j)
#pragma unroll
      for (int ks = 0; ks < 2; ++ks) {
        bf16x8 vf[4];
#pragma unroll
        for (int dt = 0; dt < 4; ++dt)
          vf[dt] = frag(VTs[h], dt * 16 + cc, ks * 4 + q4);
#pragma unroll
        for (int it = 0; it < 2; ++it) {
          FragU fu;
          fu.i[0] = pk[2 * ks][it][0];
          fu.i[1] = pk[2 * ks][it][1];
          fu.i[2] = pk[2 * ks + 1][it][0];
          fu.i[3] = pk[2 * ks + 1][it][1];
#pragma unroll
          for (int dt = 0; dt < 4; ++dt)
            o_t[dt][it] = __builtin_amdgcn_mfma_f32_16x16x32_bf16(vf[dt], fu.v,
                                                                  o_t[dt][it], 0, 0, 0);
          osum[it] = __builtin_amdgcn_mfma_f32_16x16x32_bf16(onesf.v, fu.v,
                                                             osum[it], 0, 0, 0);
        }
      }
    }
    __syncthreads();
  }
  // osum[it][0] already = full sum_j P (MFMA reduced over K); no shuffles.
  float inv[2];
#pragma unroll
  for (int it = 0; it < 2; ++it) inv[it] = 1.0f / osum[it][0];
  const int b = bh >> 4, h = bh & 15;
#pragma unroll
  for (int it = 0; it < 2; ++it) {
    const int n = it0 + w * 32 + it * 16 + cc;
    const size_t base = ((size_t)b * 2048 + n) * 1024 + h * 64 + q4 * 4;
#pragma unroll
    for (int dt = 0; dt < 4; ++dt) {
      float4 val;
      val.x = o_t[dt][it][0] * inv[it];
      val.y = o_t[dt][it][1] * inv[it];
      val.z = o_t[dt][it][2] * inv[it];
      val.w = o_t[dt][it][3] * inv[it];
      *(float4*)(out + base + dt * 16) = val;
    }
  }
}

// ---------------------------------------------------------------------------
extern "C" void kernel_launch(void* const* d_in, const int* in_sizes, int n_in,
                              void* d_out, int out_size, void* d_ws, size_t ws_size,
                              hipStream_t stream) {
  const float* x   = (const float*)d_in[0];   // (4,2048,1024)
  const float* ctx = (const float*)d_in[1];   // (4,2048,1024)
  const float* Wq  = (const float*)d_in[2];   // (1024,1024)
  const float* Wkv = (const float*)d_in[3];   // (1024,2048)
  float* out = (float*)d_out;                 // (4,2048,1024) fp32
  char* ws = (char*)d_ws;
  bf16* xb   = (bf16*)(ws);                   // 8192x1024 bf16
  bf16* cb   = (bf16*)(ws + 16777216);        // 8192x1024 bf16
  bf16* wqt  = (bf16*)(ws + 33554432);        // 1024x1024 bf16 (W^T, pre-scaled)
  bf16* wkvt = (bf16*)(ws + 35651584);        // 2048x1024 bf16
  bf16* qb   = (bf16*)(ws + 39845888);        // (64,2048,64) bf16
  bf16* kb   = (bf16*)(ws + 56623104);        // (64,2048,64) bf16
  bf16* vtb  = (bf16*)(ws + 73400320);        // (64,64,2048) bf16

  prep<<<5120, 256, 0, stream>>>((const float4*)x, (ushort4*)xb,
                                 (const float4*)ctx, (ushort4*)cb,
                                 Wq, wqt, Wkv, wkvt);
  gemm_all<<<1536, 256, 0, stream>>>(xb, cb, wqt, wkvt, qb, kb, vtb);
  attn<<<1024, 256, 0, stream>>>(qb, kb, vtb, out);
}